// Round 14
// baseline (326.966 us; speedup 1.0000x reference)
//
#include <hip/hip_runtime.h>

#define BINS 10
#define TPB  256
#define NBLK 2048

// ======================= per-element math (r4-exact, proven) =================
#define GHMC_ELEM(pk, tk, wk)                                                 \
    do {                                                                      \
        float tm_ = __builtin_fmaf((tk), -2.0f, 1.0f);                        \
        float y_  = tm_ * (pk);                                               \
        bool  v_  = ((wk) > 0.0f);                                            \
        float ye_ = v_ ? y_ : -60.0f;                                         \
        float e_  = __expf(-__builtin_fabsf(ye_));                            \
        float onep_ = 1.0f + e_;                                              \
        float bce_  = __builtin_fmaf(0.69314718055994530942f,                 \
                                     __log2f(onep_),                          \
                                     __builtin_fmaxf(ye_, 0.0f));             \
        S[0] += bce_;                                                         \
        C0   += v_ ? 1 : 0;                                                   \
        _Pragma("unroll")                                                     \
        for (int b_ = 1; b_ <= 5; ++b_) {                                     \
            bool ge_ = (ye_ >= kL[b_ - 1]);                                   \
            S[b_] += ge_ ? bce_ : 0.0f;                                       \
            cLo   += ge_ ? (1u << (6 * (b_ - 1))) : 0u;                       \
        }                                                                     \
        _Pragma("unroll")                                                     \
        for (int b_ = 6; b_ <= 9; ++b_) {                                     \
            bool ge_ = (ye_ >= kL[b_ - 1]);                                   \
            S[b_] += ge_ ? bce_ : 0.0f;                                       \
            cHi   += ge_ ? (1u << (6 * (b_ - 6))) : 0u;                       \
        }                                                                     \
    } while (0)

#define GHMC_ELEM4(P, T, W_)                                                  \
    do {                                                                      \
        GHMC_ELEM((P).x, (T).x, (W_).x);                                      \
        GHMC_ELEM((P).y, (T).y, (W_).y);                                      \
        GHMC_ELEM((P).z, (T).z, (W_).z);                                      \
        GHMC_ELEM((P).w, (T).w, (W_).w);                                      \
    } while (0)

#define GHMC_DECLS                                                            \
    const float kL[9] = { -2.1972246f, -1.3862944f, -0.84729786f,             \
                          -0.40546511f, 0.0f, 0.40546511f, 0.84729786f,       \
                          1.3862944f, 2.1972246f };                           \
    float S[BINS];                                                            \
    _Pragma("unroll") for (int b = 0; b < BINS; ++b) S[b] = 0.0f;             \
    int C0 = 0;                                                               \
    unsigned cLo = 0u, cHi = 0u;

#define GHMC_BLOCKRED                                                         \
    float lsum[BINS];                                                         \
    int   lcnt[BINS];                                                         \
    {                                                                         \
        int Cc[BINS];                                                         \
        Cc[0] = C0;                                                           \
        _Pragma("unroll")                                                     \
        for (int b = 1; b <= 5; ++b) Cc[b] = (int)((cLo >> (6*(b-1))) & 63u); \
        _Pragma("unroll")                                                     \
        for (int b = 6; b <= 9; ++b) Cc[b] = (int)((cHi >> (6*(b-6))) & 63u); \
        _Pragma("unroll")                                                     \
        for (int b = 0; b < BINS - 1; ++b) {                                  \
            lsum[b] = S[b] - S[b + 1];                                        \
            lcnt[b] = Cc[b] - Cc[b + 1];                                      \
        }                                                                     \
        lsum[BINS - 1] = S[BINS - 1];                                         \
        lcnt[BINS - 1] = Cc[BINS - 1];                                        \
    }                                                                         \
    __shared__ float s_bsum[BINS];                                            \
    __shared__ int   s_bcnt[BINS];                                            \
    if (threadIdx.x < BINS) { s_bsum[threadIdx.x] = 0.0f;                     \
                              s_bcnt[threadIdx.x] = 0; }                      \
    __syncthreads();                                                          \
    {                                                                         \
        const int lane = threadIdx.x & 63;                                    \
        _Pragma("unroll")                                                     \
        for (int b = 0; b < BINS; ++b) {                                      \
            float s = lsum[b];                                                \
            int   c = lcnt[b];                                                \
            _Pragma("unroll")                                                 \
            for (int off = 32; off > 0; off >>= 1) {                          \
                s += __shfl_xor(s, off, 64);                                  \
                c += __shfl_xor(c, off, 64);                                  \
            }                                                                 \
            if (lane == 0 && c != 0) {                                        \
                atomicAdd(&s_bsum[b], s);                                     \
                atomicAdd(&s_bcnt[b], c);                                     \
            }                                                                 \
        }                                                                     \
    }                                                                         \
    __syncthreads();

__device__ __forceinline__ void glds16(const void* g, void* l) {
    __builtin_amdgcn_global_load_lds(
        (const __attribute__((address_space(1))) void*)g,
        (__attribute__((address_space(3))) void*)l, 16, 0, 0);
}

// ======================= main (r13-exact, proven 112us, absmax 0) ============
__global__ __launch_bounds__(256) void ghmc_main(
    const float* __restrict__ pred, const float* __restrict__ targ,
    const float* __restrict__ lw,
    float* __restrict__ slot_sum, int* __restrict__ slot_cnt, int n) {

    __shared__ float4 sP[2][TPB];
    __shared__ float4 sT[2][TPB];
    __shared__ float4 sW[2][TPB];

    GHMC_DECLS

    const int nvec  = n >> 2;
    const int start = (int)(((long long)nvec * blockIdx.x) / gridDim.x);
    const int end   = (int)(((long long)nvec * (blockIdx.x + 1)) / gridDim.x);
    const int cnt4  = end - start;

    const float4* p4 = (const float4*)pred;
    const float4* t4 = (const float4*)targ;
    const float4* w4 = (const float4*)lw;

    const int wbase   = ((int)threadIdx.x >> 6) << 6;
    const int nstages = (cnt4 + TPB - 1) / TPB;

    {
        const int idx = start + (int)threadIdx.x;
        if (idx < end) {
            glds16(p4 + idx, (void*)&sP[0][wbase]);
            glds16(t4 + idx, (void*)&sT[0][wbase]);
            glds16(w4 + idx, (void*)&sW[0][wbase]);
        }
    }
    __syncthreads();

    int cur = 0;
    for (int s = 0; s < nstages; ++s) {
        if (s + 1 < nstages) {
            const int idx = start + (s + 1) * TPB + (int)threadIdx.x;
            if (idx < end) {
                glds16(p4 + idx, (void*)&sP[cur ^ 1][wbase]);
                glds16(t4 + idx, (void*)&sT[cur ^ 1][wbase]);
                glds16(w4 + idx, (void*)&sW[cur ^ 1][wbase]);
            }
        }
        {
            const int idx = start + s * TPB + (int)threadIdx.x;
            if (idx < end) {
                float4 p = sP[cur][threadIdx.x];
                float4 t = sT[cur][threadIdx.x];
                float4 w = sW[cur][threadIdx.x];
                GHMC_ELEM4(p, t, w);
            }
        }
        __syncthreads();
        cur ^= 1;
    }

    {
        int rem  = n & 3;
        int gtid = blockIdx.x * TPB + (int)threadIdx.x;
        if (gtid < rem) {
            int idx = (nvec << 2) + gtid;
            float pk = pred[idx], tk = targ[idx], wk = lw[idx];
            GHMC_ELEM(pk, tk, wk);
        }
    }

    GHMC_BLOCKRED

    if (threadIdx.x < BINS) {
        slot_sum[threadIdx.x * gridDim.x + blockIdx.x] = s_bsum[threadIdx.x];
        slot_cnt[threadIdx.x * gridDim.x + blockIdx.x] = s_bcnt[threadIdx.x];
    }
}

// ======================= diagnostic probe 1: pure-read BW ====================
// Same 3-stream float4 pattern/grid as main, ~3 VALU/element (XOR keeps every
// byte live -> no DCE). Measures achievable read BW for THIS pattern (rule:
// never infer a ceiling from your own failed attempts; this is the reference).
__global__ __launch_bounds__(256) void bw_probe(
    const uint4* __restrict__ a, const uint4* __restrict__ b,
    const uint4* __restrict__ c, uint4* __restrict__ slot, int n4) {
    const int start = (int)(((long long)n4 * blockIdx.x) / gridDim.x);
    const int end   = (int)(((long long)n4 * (blockIdx.x + 1)) / gridDim.x);
    unsigned ax = 0, ay = 0, az = 0, aw = 0;
    for (int i = start + (int)threadIdx.x; i < end; i += TPB) {
        uint4 x = a[i], y = b[i], z = c[i];
        ax ^= x.x ^ y.x ^ z.x;
        ay ^= x.y ^ y.y ^ z.y;
        az ^= x.z ^ y.z ^ z.z;
        aw ^= x.w ^ y.w ^ z.w;
    }
#pragma unroll
    for (int off = 32; off > 0; off >>= 1) {
        ax ^= __shfl_xor(ax, off, 64);
        ay ^= __shfl_xor(ay, off, 64);
        az ^= __shfl_xor(az, off, 64);
        aw ^= __shfl_xor(aw, off, 64);
    }
    __shared__ uint4 swv[TPB / 64];
    if ((threadIdx.x & 63) == 0)
        swv[threadIdx.x >> 6] = make_uint4(ax, ay, az, aw);
    __syncthreads();
    if (threadIdx.x == 0) {
        uint4 r = swv[0];
#pragma unroll
        for (int v = 1; v < TPB / 64; ++v) {
            r.x ^= swv[v].x; r.y ^= swv[v].y;
            r.z ^= swv[v].z; r.w ^= swv[v].w;
        }
        slot[blockIdx.x] = r;
    }
}

// ======================= diagnostic probe 2: math, no bins ===================
// Full softplus path (~20 VALU/element) but no threshold/bin accumulation.
// Mid-point of the time-vs-VALU curve.
__global__ __launch_bounds__(256) void math_probe(
    const float* __restrict__ pred, const float* __restrict__ targ,
    const float* __restrict__ lw, float* __restrict__ slot, int n) {
    const int nvec  = n >> 2;
    const int start = (int)(((long long)nvec * blockIdx.x) / gridDim.x);
    const int end   = (int)(((long long)nvec * (blockIdx.x + 1)) / gridDim.x);
    const float4* p4 = (const float4*)pred;
    const float4* t4 = (const float4*)targ;
    const float4* w4 = (const float4*)lw;
    float acc = 0.0f;
    for (int i = start + (int)threadIdx.x; i < end; i += TPB) {
        float4 p = p4[i], t = t4[i], w = w4[i];
        const float* pp = (const float*)&p;
        const float* tt = (const float*)&t;
        const float* ww = (const float*)&w;
#pragma unroll
        for (int k = 0; k < 4; ++k) {
            float tm = __builtin_fmaf(tt[k], -2.0f, 1.0f);
            float y  = tm * pp[k];
            float ye = (ww[k] > 0.0f) ? y : -60.0f;
            float e  = __expf(-__builtin_fabsf(ye));
            acc += __builtin_fmaf(0.69314718055994530942f,
                                  __log2f(1.0f + e),
                                  __builtin_fmaxf(ye, 0.0f));
        }
    }
#pragma unroll
    for (int off = 32; off > 0; off >>= 1) acc += __shfl_xor(acc, off, 64);
    __shared__ float swv[TPB / 64];
    if ((threadIdx.x & 63) == 0) swv[threadIdx.x >> 6] = acc;
    __syncthreads();
    if (threadIdx.x == 0) {
        float r = 0.0f;
#pragma unroll
        for (int v = 0; v < TPB / 64; ++v) r += swv[v];
        slot[blockIdx.x] = r;
    }
}

// ======================= finalize (r13-exact) ================================
__global__ __launch_bounds__(256) void ghmc_finalize(
    const float* __restrict__ slot_sum, const int* __restrict__ slot_cnt,
    float* __restrict__ out, int nblk) {
    float ps[BINS];
    int   pc[BINS];
#pragma unroll
    for (int b = 0; b < BINS; ++b) { ps[b] = 0.0f; pc[b] = 0; }
    for (int i = (int)threadIdx.x; i < nblk; i += TPB) {
#pragma unroll
        for (int b = 0; b < BINS; ++b) {
            ps[b] += slot_sum[b * nblk + i];
            pc[b] += slot_cnt[b * nblk + i];
        }
    }
    __shared__ float s_s[BINS];
    __shared__ int   s_c[BINS];
    if (threadIdx.x < BINS) { s_s[threadIdx.x] = 0.0f; s_c[threadIdx.x] = 0; }
    __syncthreads();
    const int lane = threadIdx.x & 63;
#pragma unroll
    for (int b = 0; b < BINS; ++b) {
        float s = ps[b];
        int   c = pc[b];
#pragma unroll
        for (int off = 32; off > 0; off >>= 1) {
            s += __shfl_xor(s, off, 64);
            c += __shfl_xor(c, off, 64);
        }
        if (lane == 0) { atomicAdd(&s_s[b], s); atomicAdd(&s_c[b], c); }
    }
    __syncthreads();
    if (threadIdx.x == 0) {
        float acc = 0.0f;
        int nb = 0;
        for (int b = 0; b < BINS; ++b) {
            int c = s_c[b];
            if (c > 0) { nb += 1; acc += s_s[b] / (float)c; }
        }
        out[0] = (nb > 0) ? (acc / (float)nb) : 0.0f;  // LOSS_WEIGHT = 1
    }
}

extern "C" void kernel_launch(void* const* d_in, const int* in_sizes, int n_in,
                              void* d_out, int out_size, void* d_ws, size_t ws_size,
                              hipStream_t stream) {
    const float* pred = (const float*)d_in[0];
    const float* targ = (const float*)d_in[1];
    const float* lw   = (const float*)d_in[2];
    float* out = (float*)d_out;
    const int n = in_sizes[0];   // 262144*80 = 20,971,520

    // ws layout (bytes):
    //   [0,       81920)  main slot_sum   (2048 x 10 x 4)
    //   [81920,  163840)  main slot_cnt
    //   [163840, 196608)  bw_probe slots  (2048 x 16)
    //   [196608, 204800)  math_probe slots(2048 x 4)
    float* slot_sum = (float*)d_ws;
    int*   slot_cnt = (int*)((char*)d_ws + 81920);

    ghmc_main<<<NBLK, TPB, 0, stream>>>(pred, targ, lw, slot_sum, slot_cnt, n);

    if (ws_size >= 204800) {   // diagnostics only if workspace allows
        uint4* bw_slot   = (uint4*)((char*)d_ws + 163840);
        float* math_slot = (float*)((char*)d_ws + 196608);
        bw_probe<<<NBLK, TPB, 0, stream>>>((const uint4*)pred, (const uint4*)targ,
                                           (const uint4*)lw, bw_slot, n >> 2);
        math_probe<<<NBLK, TPB, 0, stream>>>(pred, targ, lw, math_slot, n);
    }

    ghmc_finalize<<<1, TPB, 0, stream>>>(slot_sum, slot_cnt, out, NBLK);
}

// Round 15
// 256.019 us; speedup vs baseline: 1.2771x; 1.2771x over previous
//
#include <hip/hip_runtime.h>

#define BINS 10
#define TPB  256
#define NBLK 2048

// ======================= per-element update, VCC-FREE bins ===================
// r14 verdict: pure-read probe ~34us, math-only probe ~34us, main 112us -> the
// +78us is ONLY the 9-bin cmp/cndmask accumulation. Theory: all 9 v_cmp/
// v_cndmask pairs serialize on the single VCC register (~70 stall-cyc/elem that
// 3.6 waves/SIMD can't hide). Fix: sign-bit integer masks, no vcc:
//   d = ye - L;  nm = (int)bits(d)>>31   (-1 if ye<L, 0 if ye>=L)
//   S[b] += bits(bce) & ~nm              (adds +0.0f when lt: bit-identical)
//   Mneg[b] += nm;  cnt_ge[b] = nproc + Mneg[b]
// Subnormal/FTZ safe: flushed d keeps its sign bit; d is never NaN.
// Invalid (w==0): ye=-60 -> lt all thresholds AND softplus(-60)==+0.0f exactly.
// Valid count: c0f += w (w in {0,1}, <=41/lane: exact in f32).
#define GHMC_ELEM(pk, tk, wk)                                                 \
    do {                                                                      \
        float tm_ = __builtin_fmaf((tk), -2.0f, 1.0f);                        \
        float y_  = tm_ * (pk);                                               \
        bool  v_  = ((wk) > 0.0f);        /* sole vcc use per element */      \
        float ye_ = v_ ? y_ : -60.0f;                                         \
        float e_  = __expf(-__builtin_fabsf(ye_));                            \
        float onep_ = 1.0f + e_;                                              \
        float bce_  = __builtin_fmaf(0.69314718055994530942f,                 \
                                     __log2f(onep_),                          \
                                     __builtin_fmaxf(ye_, 0.0f));             \
        unsigned bb_ = __float_as_uint(bce_);                                 \
        S[0]  += bce_;                                                        \
        c0f   += (wk);                                                        \
        nproc += 1;                                                           \
        _Pragma("unroll")                                                     \
        for (int b_ = 1; b_ < BINS; ++b_) {                                   \
            float d_ = ye_ - kL[b_ - 1];                                      \
            int  nm_ = ((int)__float_as_uint(d_)) >> 31;                      \
            Mneg[b_ - 1] += nm_;                                              \
            S[b_] += __uint_as_float(~(unsigned)nm_ & bb_);                   \
        }                                                                     \
    } while (0)

#define GHMC_ELEM4(P, T, W_)                                                  \
    do {                                                                      \
        GHMC_ELEM((P).x, (T).x, (W_).x);                                      \
        GHMC_ELEM((P).y, (T).y, (W_).y);                                      \
        GHMC_ELEM((P).z, (T).z, (W_).z);                                      \
        GHMC_ELEM((P).w, (T).w, (W_).w);                                      \
    } while (0)

#define GHMC_DECLS                                                            \
    const float kL[9] = { -2.1972246f, -1.3862944f, -0.84729786f,             \
                          -0.40546511f, 0.0f, 0.40546511f, 0.84729786f,       \
                          1.3862944f, 2.1972246f };                           \
    float S[BINS];                                                            \
    _Pragma("unroll") for (int b = 0; b < BINS; ++b) S[b] = 0.0f;             \
    int Mneg[BINS - 1];                                                       \
    _Pragma("unroll") for (int b = 0; b < BINS - 1; ++b) Mneg[b] = 0;         \
    float c0f = 0.0f;                                                         \
    int nproc = 0;

// cumulative -> per-bin; wave butterfly; block LDS combine -> s_bsum/s_bcnt
#define GHMC_BLOCKRED                                                         \
    float lsum[BINS];                                                         \
    int   lcnt[BINS];                                                         \
    {                                                                         \
        int Cc[BINS];                                                         \
        Cc[0] = (int)c0f;                                                     \
        _Pragma("unroll")                                                     \
        for (int b = 1; b < BINS; ++b) Cc[b] = nproc + Mneg[b - 1];           \
        _Pragma("unroll")                                                     \
        for (int b = 0; b < BINS - 1; ++b) {                                  \
            lsum[b] = S[b] - S[b + 1];                                        \
            lcnt[b] = Cc[b] - Cc[b + 1];                                      \
        }                                                                     \
        lsum[BINS - 1] = S[BINS - 1];                                         \
        lcnt[BINS - 1] = Cc[BINS - 1];                                        \
    }                                                                         \
    __shared__ float s_bsum[BINS];                                            \
    __shared__ int   s_bcnt[BINS];                                            \
    if (threadIdx.x < BINS) { s_bsum[threadIdx.x] = 0.0f;                     \
                              s_bcnt[threadIdx.x] = 0; }                      \
    __syncthreads();                                                          \
    {                                                                         \
        const int lane = threadIdx.x & 63;                                    \
        _Pragma("unroll")                                                     \
        for (int b = 0; b < BINS; ++b) {                                      \
            float s = lsum[b];                                                \
            int   c = lcnt[b];                                                \
            _Pragma("unroll")                                                 \
            for (int off = 32; off > 0; off >>= 1) {                          \
                s += __shfl_xor(s, off, 64);                                  \
                c += __shfl_xor(c, off, 64);                                  \
            }                                                                 \
            if (lane == 0 && c != 0) {                                        \
                atomicAdd(&s_bsum[b], s);                                     \
                atomicAdd(&s_bcnt[b], c);                                     \
            }                                                                 \
        }                                                                     \
    }                                                                         \
    __syncthreads();

// ======================= main: r4 register-prefetch loop =====================
// (proven tail-free at 112us in r12-clean; tail confound resolved r12: the
// fused ticket/fence ending cost a constant ~270us and is gone permanently)
__global__ __launch_bounds__(256) void ghmc_main(
    const float* __restrict__ pred, const float* __restrict__ targ,
    const float* __restrict__ lw,
    float* __restrict__ slot_sum, int* __restrict__ slot_cnt, int n) {

    GHMC_DECLS

    const int nvec  = n >> 2;
    const int start = (int)(((long long)nvec * blockIdx.x) / gridDim.x);
    const int end   = (int)(((long long)nvec * (blockIdx.x + 1)) / gridDim.x);

    const float4* p4 = (const float4*)pred;
    const float4* t4 = (const float4*)targ;
    const float4* w4 = (const float4*)lw;

    // depth-1 register prefetch: next batch in flight during current compute
    int i = start + (int)threadIdx.x;
    if (i < end) {
        float4 p = p4[i], t = t4[i], w = w4[i];
        for (int j = i + TPB; j < end; j += TPB) {
            float4 pn = p4[j], tn = t4[j], wn = w4[j];
            GHMC_ELEM4(p, t, w);
            p = pn; t = tn; w = wn;
        }
        GHMC_ELEM4(p, t, w);
    }
    // scalar tail (n not divisible by 4)
    {
        int rem  = n & 3;
        int gtid = blockIdx.x * TPB + (int)threadIdx.x;
        if (gtid < rem) {
            int idx = (nvec << 2) + gtid;
            float pk = pred[idx], tk = targ[idx], wk = lw[idx];
            GHMC_ELEM(pk, tk, wk);
        }
    }

    GHMC_BLOCKRED

    // plain stores to private slots (always overwritten -> poison-safe, no
    // zero kernel, no global atomics, no fence). [bin][block] for coalesced
    // finalize reads.
    if (threadIdx.x < BINS) {
        slot_sum[threadIdx.x * gridDim.x + blockIdx.x] = s_bsum[threadIdx.x];
        slot_cnt[threadIdx.x * gridDim.x + blockIdx.x] = s_bcnt[threadIdx.x];
    }
}

// ======================= finalize: reduce 2048 slots =========================
__global__ __launch_bounds__(256) void ghmc_finalize(
    const float* __restrict__ slot_sum, const int* __restrict__ slot_cnt,
    float* __restrict__ out, int nblk) {
    float ps[BINS];
    int   pc[BINS];
#pragma unroll
    for (int b = 0; b < BINS; ++b) { ps[b] = 0.0f; pc[b] = 0; }
    for (int i = (int)threadIdx.x; i < nblk; i += TPB) {
#pragma unroll
        for (int b = 0; b < BINS; ++b) {
            ps[b] += slot_sum[b * nblk + i];
            pc[b] += slot_cnt[b * nblk + i];
        }
    }
    __shared__ float s_s[BINS];
    __shared__ int   s_c[BINS];
    if (threadIdx.x < BINS) { s_s[threadIdx.x] = 0.0f; s_c[threadIdx.x] = 0; }
    __syncthreads();
    const int lane = threadIdx.x & 63;
#pragma unroll
    for (int b = 0; b < BINS; ++b) {
        float s = ps[b];
        int   c = pc[b];
#pragma unroll
        for (int off = 32; off > 0; off >>= 1) {
            s += __shfl_xor(s, off, 64);
            c += __shfl_xor(c, off, 64);
        }
        if (lane == 0) { atomicAdd(&s_s[b], s); atomicAdd(&s_c[b], c); }
    }
    __syncthreads();
    if (threadIdx.x == 0) {
        float acc = 0.0f;
        int nb = 0;
        for (int b = 0; b < BINS; ++b) {
            int c = s_c[b];
            if (c > 0) { nb += 1; acc += s_s[b] / (float)c; }
        }
        out[0] = (nb > 0) ? (acc / (float)nb) : 0.0f;  // LOSS_WEIGHT = 1
    }
}

extern "C" void kernel_launch(void* const* d_in, const int* in_sizes, int n_in,
                              void* d_out, int out_size, void* d_ws, size_t ws_size,
                              hipStream_t stream) {
    const float* pred = (const float*)d_in[0];
    const float* targ = (const float*)d_in[1];
    const float* lw   = (const float*)d_in[2];
    float* out = (float*)d_out;
    const int n = in_sizes[0];   // 262144*80 = 20,971,520

    // ws: [0, 81920) slot_sum (2048 x 10 x 4B); [81920, 163840) slot_cnt
    float* slot_sum = (float*)d_ws;
    int*   slot_cnt = (int*)((char*)d_ws + 81920);

    ghmc_main<<<NBLK, TPB, 0, stream>>>(pred, targ, lw, slot_sum, slot_cnt, n);
    ghmc_finalize<<<1, TPB, 0, stream>>>(slot_sum, slot_cnt, out, NBLK);
}